// Round 5
// baseline (613.522 us; speedup 1.0000x reference)
//
#include <hip/hip_runtime.h>

typedef unsigned short u16;
typedef _Float16 f16;
typedef __attribute__((ext_vector_type(8))) _Float16 f16x8;
typedef __attribute__((ext_vector_type(4))) float f32x4;

static __device__ __forceinline__ f32x4 mfma16h(f16x8 a, f16x8 b, f32x4 c) {
  return __builtin_amdgcn_mfma_f32_16x16x32_f16(a, b, c, 0, 0, 0);
}
// async global->LDS, 16B/lane; dest = wave-uniform base (+ lane*16 implicit)
static __device__ __forceinline__ void gl_lds16(const char* g, char* l) {
  __builtin_amdgcn_global_load_lds(
      (const __attribute__((address_space(1))) unsigned int*)g,
      (__attribute__((address_space(3))) unsigned int*)l, 16, 0, 0);
}
static __device__ __forceinline__ u16 f16bits(float f) {
  union { f16 h; u16 u; } v; v.h = (f16)f; return v.u;
}

// ============================================================
// Kernel 0: split x -> xh, xl (fp16 hi/lo). 8192 x 256.
// ============================================================
__global__ __launch_bounds__(256) void splitx_kernel(
    const float* __restrict__ x, u16* __restrict__ xh, u16* __restrict__ xl) {
  int i = (blockIdx.x * 256 + threadIdx.x) * 8;
  float4 a = *(const float4*)(x + i);
  float4 b = *(const float4*)(x + i + 4);
  float ff[8] = {a.x, a.y, a.z, a.w, b.x, b.y, b.z, b.w};
  union { u16 s[8]; int4 v; } H, L;
  #pragma unroll
  for (int e = 0; e < 8; e++) {
    f16 h = (f16)ff[e];
    union { f16 h; u16 u; } uh; uh.h = h; H.s[e] = uh.u;
    f16 lo = (f16)(ff[e] - (float)h);
    union { f16 h; u16 u; } ul; ul.h = lo; L.s[e] = ul.u;
  }
  *(int4*)(xh + i) = H.v;
  *(int4*)(xl + i) = L.v;
}

// ============================================================
// Kernel 1: W^T fp16 (hi only) into B-frag swizzled layout.
// Per matrix 128KB: [col 256][512B row: 16B slot s' = (s + 2*col)&31,
// s = k>>3, within-slot (k&7)*2].
// ============================================================
__global__ __launch_bounds__(256) void prep_w_kernel(
    const float* __restrict__ Wq, const float* __restrict__ Wk,
    const float* __restrict__ Wv, char* __restrict__ wout) {
  int idx = blockIdx.x * 256 + threadIdx.x;   // 0..196607
  int mm = idx >> 16;
  int o  = idx & 65535;
  int col = o >> 8, e = o & 255;
  const float* W = (mm == 0) ? Wq : ((mm == 1) ? Wk : Wv);
  float v = W[e * 256 + col];
  size_t b0 = (size_t)mm * 131072 + col * 512
            + ((((e >> 3) + 2 * col) & 31) << 4) + ((e & 7) << 1);
  *(u16*)(wout + b0) = f16bits(v);
}

// ============================================================
// Kernel 2: QKV projection. Grid (512, 3) x 512 thr.
// Block = 128 tokens x one matrix; whole weight (128KB) staged ONCE in LDS.
// Wave = 16 tokens; x hi/lo frags in regs; 2-term fp16 MFMA.
// Outputs: qh/ql [tok][256] fp16; kh [tok][512B swizzled] fp16 (hi only);
// vt tiled [b][tile32][256d][32t] fp16 XOR-swizzled.
// ============================================================
__global__ __launch_bounds__(512, 2) void proj_kernel(
    const u16* __restrict__ xh_g, const u16* __restrict__ xl_g,
    const float* __restrict__ bq, const float* __restrict__ bk,
    const float* __restrict__ bv, const char* __restrict__ wspl,
    u16* __restrict__ qh, u16* __restrict__ ql,
    char* __restrict__ kh, char* __restrict__ vt) {
  __shared__ __align__(16) char wlds[131072];
  const int tid = threadIdx.x;
  const int l = tid & 63, w = tid >> 6;
  const int l15 = l & 15, l4 = l >> 4;
  const int mat = blockIdx.y;
  const int tok0 = blockIdx.x * 128 + w * 16;

  // ---- stage whole weight matrix (128KB) ----
  {
    const char* wsrc = wspl + (size_t)mat * 131072;
    #pragma unroll
    for (int i = 0; i < 16; i++)
      gl_lds16(wsrc + i * 8192 + w * 1024 + l * 16, wlds + i * 8192 + w * 1024);
  }

  // ---- x hi/lo A-frags (16 tok/wave) ----
  f16x8 xh8[8], xl8[8];
  {
    const char* xph = (const char*)xh_g + (size_t)(tok0 + l15) * 512 + l4 * 16;
    const char* xpl = (const char*)xl_g + (size_t)(tok0 + l15) * 512 + l4 * 16;
    #pragma unroll
    for (int kk = 0; kk < 8; kk++) {
      xh8[kk] = *(const f16x8*)(xph + kk * 64);
      xl8[kk] = *(const f16x8*)(xpl + kk * 64);
    }
  }
  __syncthreads();   // weights staged (syncthreads drains vmcnt)

  f32x4 acc[16];
  #pragma unroll
  for (int i = 0; i < 16; i++) acc[i] = (f32x4){0.f, 0.f, 0.f, 0.f};

  #pragma unroll
  for (int kk = 0; kk < 8; kk++) {
    f16x8 ah = xh8[kk];
    f16x8 al = xl8[kk];
    #pragma unroll
    for (int ct = 0; ct < 16; ct++) {
      int off = (ct * 16 + l15) * 512 + (((kk * 4 + l4 + 2 * l15) & 31) << 4);
      f16x8 bh = *(const f16x8*)(wlds + off);
      if (mat < 2) {
        acc[ct] = mfma16h(ah, bh, acc[ct]);
        acc[ct] = mfma16h(al, bh, acc[ct]);
      } else {
        acc[ct] = mfma16h(bh, ah, acc[ct]);   // swapped: C rows = d, cols = tok
        acc[ct] = mfma16h(bh, al, acc[ct]);
      }
    }
  }

  // ---- epilogues ----
  if (mat == 0) {
    #pragma unroll
    for (int ct = 0; ct < 16; ct++) {
      int col = ct * 16 + l15;
      float bb = bq[col];
      #pragma unroll
      for (int j = 0; j < 4; j++) {
        size_t tok = (size_t)(tok0 + l4 * 4 + j);
        float v = acc[ct][j] + bb;
        f16 hi = (f16)v;
        union { f16 h; u16 u; } uh; uh.h = hi;
        union { f16 h; u16 u; } ul; ul.h = (f16)(v - (float)hi);
        qh[tok * 256 + col] = uh.u;
        ql[tok * 256 + col] = ul.u;
      }
    }
  } else if (mat == 1) {
    #pragma unroll
    for (int ct = 0; ct < 16; ct++) {
      int col = ct * 16 + l15;
      float bb = bk[col];
      #pragma unroll
      for (int j = 0; j < 4; j++) {
        size_t tok = (size_t)(tok0 + l4 * 4 + j);
        float v = acc[ct][j] + bb;
        size_t off = tok * 512 + ((((col >> 3) + 2 * (int)tok) & 31) << 4)
                   + ((col & 7) << 1);
        *(u16*)(kh + off) = f16bits(v);
      }
    }
  } else {
    int t = tok0 + l15;
    int b2 = t >> 10, tile = (t >> 5) & 31, trel = t & 31;
    size_t tbase = (size_t)b2 * 524288 + (size_t)tile * 16384
                 + ((trel & 7) << 1);
    int tsl = (trel >> 3) << 4;
    #pragma unroll
    for (int ct = 0; ct < 16; ct++) {
      #pragma unroll
      for (int j = 0; j < 4; j++) {
        int d = ct * 16 + l4 * 4 + j;
        float v = acc[ct][j] + bv[d];
        size_t off = tbase + ((d * 64 + tsl) ^ ((d & 7) << 4));
        *(u16*)(vt + off) = f16bits(v);
      }
    }
  }
}

// ============================================================
// Kernel 3: flash attention. Grid 512 x 512 thr; block = 128 q rows.
// KVBLK=64. T14 staging: global->reg loads for t+1 issued before the
// barrier, ds_write at top of t+1 (compiler-counted vmcnt at use).
// ONE raw s_barrier + lgkmcnt(0) per tile (no vmcnt drain).
// 2-term fp16 scores; defer-max THR=8; fp16 PV.
// ============================================================
__global__ __launch_bounds__(512, 2) void attn_kernel(
    const u16* __restrict__ qh_g, const u16* __restrict__ ql_g,
    const char* __restrict__ kh_g, const char* __restrict__ vt_g,
    float* __restrict__ out) {
  __shared__ __align__(16) char lds[147456];
  // 2 bufs x 64KB: kh [64][512B] (32KB) | vt 2 subtiles [256][64B] (32KB)
  char* p_lds = lds + 131072;   // 8 waves x 2KB

  const int tid = threadIdx.x;
  const int l = tid & 63, w = tid >> 6;
  const int l15 = l & 15, l4 = l >> 4;
  int wg = blockIdx.x;
  int b  = (wg & 7) * 8 + (wg >> 6);
  int qt = (wg >> 3) & 7;

  // ---- Q fragments (16 rows/wave, hi/lo fp16) ----
  const int q0 = qt * 128 + w * 16;
  const char* qhp = (const char*)qh_g + (size_t)(b * 1024 + q0 + l15) * 512 + l4 * 16;
  const char* qlp = (const char*)ql_g + (size_t)(b * 1024 + q0 + l15) * 512 + l4 * 16;
  f16x8 qfh[8], qfl[8];
  #pragma unroll
  for (int kk = 0; kk < 8; kk++) {
    qfh[kk] = *(const f16x8*)(qhp + kk * 64);
    qfl[kk] = *(const f16x8*)(qlp + kk * 64);
  }

  f32x4 O[16];
  #pragma unroll
  for (int i = 0; i < 16; i++) O[i] = (f32x4){0.f, 0.f, 0.f, 0.f};
  float mrow[4] = {-1e30f, -1e30f, -1e30f, -1e30f};
  float lrow[4] = {0.f, 0.f, 0.f, 0.f};

  const char* khb = kh_g + (size_t)b * 524288;
  const char* vtb = vt_g + (size_t)b * 524288;
  char* pw = p_lds + w * 2048;

  // ---- prologue: load tile 0 into regs ----
  int4 kreg[4], vreg[4];
  #pragma unroll
  for (int i = 0; i < 4; i++) {
    kreg[i] = *(const int4*)(khb + i * 8192 + tid * 16);
    vreg[i] = *(const int4*)(vtb + i * 8192 + tid * 16);
  }

  for (int t0 = 0; t0 < 1024; t0 += 64) {
    char* buf = lds + ((t0 >> 6) & 1) * 65536;
    // ---- write staged regs -> LDS ----
    #pragma unroll
    for (int i = 0; i < 4; i++) {
      *(int4*)(buf + i * 8192 + tid * 16) = kreg[i];
      *(int4*)(buf + 32768 + i * 8192 + tid * 16) = vreg[i];
    }
    // ---- issue next tile's loads (in flight across compute) ----
    if (t0 + 64 < 1024) {
      const char* ks = khb + (size_t)(t0 + 64) * 512;
      const char* vs = vtb + (size_t)((t0 + 64) >> 5) * 16384;
      #pragma unroll
      for (int i = 0; i < 4; i++) {
        kreg[i] = *(const int4*)(ks + i * 8192 + tid * 16);
        vreg[i] = *(const int4*)(vs + i * 8192 + tid * 16);
      }
    }
    asm volatile("s_waitcnt lgkmcnt(0)" ::: "memory");
    __builtin_amdgcn_s_barrier();
    __builtin_amdgcn_sched_barrier(0);

    char* kh_lds = buf;
    char* vt_lds = buf + 32768;

    // ---- scores: S[16q][64t], 2-term fp16 ----
    f32x4 sacc[4];
    #pragma unroll
    for (int c = 0; c < 4; c++) sacc[c] = (f32x4){0.f, 0.f, 0.f, 0.f};
    __builtin_amdgcn_s_setprio(1);
    #pragma unroll
    for (int kk = 0; kk < 8; kk++) {
      int so = ((kk * 4 + l4 + 2 * l15) & 31) << 4;
      #pragma unroll
      for (int c = 0; c < 4; c++) {
        f16x8 bh = *(const f16x8*)(kh_lds + (c * 16 + l15) * 512 + so);
        sacc[c] = mfma16h(qfh[kk], bh, sacc[c]);
        sacc[c] = mfma16h(qfl[kk], bh, sacc[c]);
      }
    }
    __builtin_amdgcn_s_setprio(0);

    // ---- online softmax with defer-max (THR=8) ----
    float p[4][4];
    {
      bool need = false;
      float lmax[4];
      #pragma unroll
      for (int j = 0; j < 4; j++) {
        lmax[j] = fmaxf(fmaxf(sacc[0][j], sacc[1][j]),
                        fmaxf(sacc[2][j], sacc[3][j]));
        need = need || (lmax[j] > mrow[j] + 8.f);
      }
      if (__any(need)) {
        float scv[4];
        #pragma unroll
        for (int j = 0; j < 4; j++) {
          float mx = lmax[j];
          mx = fmaxf(mx, __shfl_xor(mx, 1));
          mx = fmaxf(mx, __shfl_xor(mx, 2));
          mx = fmaxf(mx, __shfl_xor(mx, 4));
          mx = fmaxf(mx, __shfl_xor(mx, 8));
          float mn = fmaxf(mrow[j], mx);
          scv[j] = __expf(mrow[j] - mn);
          mrow[j] = mn;
          lrow[j] *= scv[j];
        }
        #pragma unroll
        for (int i = 0; i < 16; i++) {
          O[i][0] *= scv[0]; O[i][1] *= scv[1];
          O[i][2] *= scv[2]; O[i][3] *= scv[3];
        }
      }
      #pragma unroll
      for (int j = 0; j < 4; j++) {
        float rs = 0.f;
        #pragma unroll
        for (int c = 0; c < 4; c++) {
          p[c][j] = __expf(sacc[c][j] - mrow[j]);
          rs += p[c][j];
        }
        rs += __shfl_xor(rs, 1);
        rs += __shfl_xor(rs, 2);
        rs += __shfl_xor(rs, 4);
        rs += __shfl_xor(rs, 8);
        lrow[j] += rs;
      }
    }

    // ---- P -> per-wave LDS (fp16), re-fragment for PV ----
    #pragma unroll
    for (int j = 0; j < 4; j++) {
      int row = l4 * 4 + j;
      int base = row << 7;
      int sw = (row & 7) << 4;
      #pragma unroll
      for (int c = 0; c < 4; c++)
        *(u16*)(pw + base + ((((c * 16 + l15) << 1)) ^ sw)) = f16bits(p[c][j]);
    }
    asm volatile("s_waitcnt lgkmcnt(0)" ::: "memory");
    __builtin_amdgcn_sched_barrier(0);
    int psw = (l15 & 7) << 4;
    f16x8 pa0 = *(const f16x8*)(pw + (l15 << 7) + ((l4 * 16) ^ psw));
    f16x8 pa1 = *(const f16x8*)(pw + (l15 << 7) + ((64 + l4 * 16) ^ psw));

    // ---- PV: O += P * V ----
    __builtin_amdgcn_s_setprio(1);
    #pragma unroll
    for (int dt = 0; dt < 16; dt++) {
      int d = dt * 16 + l15;
      int vo = (d * 64 + l4 * 16) ^ ((d & 7) << 4);
      f16x8 vb0 = *(const f16x8*)(vt_lds + vo);
      f16x8 vb1 = *(const f16x8*)(vt_lds + 16384 + vo);
      O[dt] = mfma16h(pa0, vb0, O[dt]);
      O[dt] = mfma16h(pa1, vb1, O[dt]);
    }
    __builtin_amdgcn_s_setprio(0);
  }

  // ---- epilogue ----
  float inv[4];
  #pragma unroll
  for (int j = 0; j < 4; j++) inv[j] = 1.0f / lrow[j];
  #pragma unroll
  for (int dt = 0; dt < 16; dt++) {
    #pragma unroll
    for (int j = 0; j < 4; j++) {
      size_t orow = (size_t)(b * 1024 + q0 + l4 * 4 + j);
      out[orow * 256 + dt * 16 + l15] = O[dt][j] * inv[j];
    }
  }
}

// ============================================================
extern "C" void kernel_launch(void* const* d_in, const int* in_sizes, int n_in,
                              void* d_out, int out_size, void* d_ws, size_t ws_size,
                              hipStream_t stream) {
  (void)in_sizes; (void)n_in; (void)out_size; (void)ws_size;
  const float* x  = (const float*)d_in[0];
  const float* Wq = (const float*)d_in[1];
  const float* bq = (const float*)d_in[2];
  const float* Wk = (const float*)d_in[3];
  const float* bk = (const float*)d_in[4];
  const float* Wv = (const float*)d_in[5];
  const float* bv = (const float*)d_in[6];
  float* out = (float*)d_out;
  char* ws = (char*)d_ws;

  const size_t M32 = 33554432;
  u16* xh  = (u16*)(ws);
  u16* xl  = (u16*)(ws + M32);
  u16* qh  = (u16*)(ws + 2 * M32);
  u16* ql  = (u16*)(ws + 3 * M32);
  char* kh = (char*)(ws + 4 * M32);
  char* vt = (char*)(ws + 5 * M32);
  char* wsp = (char*)(ws + 6 * M32);   // 384KB fp16 weights

  splitx_kernel<<<dim3(8192), dim3(256), 0, stream>>>(x, xh, xl);
  prep_w_kernel<<<dim3(768), dim3(256), 0, stream>>>(Wq, Wk, Wv, wsp);
  proj_kernel<<<dim3(512, 3), dim3(512), 0, stream>>>(
      xh, xl, bq, bk, bv, wsp, qh, ql, kh, vt);
  attn_kernel<<<dim3(512), dim3(512), 0, stream>>>(qh, ql, kh, vt, out);
}

// Round 7
// 347.859 us; speedup vs baseline: 1.7637x; 1.7637x over previous
//
#include <hip/hip_runtime.h>

typedef unsigned short u16;
typedef _Float16 f16;
typedef __attribute__((ext_vector_type(8))) _Float16 f16x8;
typedef __attribute__((ext_vector_type(4))) float f32x4;

static __device__ __forceinline__ f32x4 mfma16h(f16x8 a, f16x8 b, f32x4 c) {
  return __builtin_amdgcn_mfma_f32_16x16x32_f16(a, b, c, 0, 0, 0);
}
// async global->LDS, 16B/lane; dest = wave-uniform base (+ lane*16 implicit)
static __device__ __forceinline__ void gl_lds16(const char* g, char* l) {
  __builtin_amdgcn_global_load_lds(
      (const __attribute__((address_space(1))) unsigned int*)g,
      (__attribute__((address_space(3))) unsigned int*)l, 16, 0, 0);
}
static __device__ __forceinline__ u16 f16bits(float f) {
  union { f16 h; u16 u; } v; v.h = (f16)f; return v.u;
}

// ============================================================
// Kernel 1: W^T fp16 into 6 x 64KB staging slabs.
// slab = mat*2 + (col>>7); within: [lcol 128][512B: slot s'=(s+2*col)&31,
// s = k>>3, byte (k&7)*2].
// ============================================================
__global__ __launch_bounds__(256) void prep_w_kernel(
    const float* __restrict__ Wq, const float* __restrict__ Wk,
    const float* __restrict__ Wv, char* __restrict__ wout) {
  int idx = blockIdx.x * 256 + threadIdx.x;   // 0..196607
  int mm = idx >> 16;
  int o  = idx & 65535;
  int col = o >> 8, e = o & 255;
  const float* W = (mm == 0) ? Wq : ((mm == 1) ? Wk : Wv);
  float v = W[e * 256 + col];
  int slab = mm * 2 + (col >> 7);
  int lcol = col & 127;
  size_t b0 = (size_t)slab * 65536 + lcol * 512
            + ((((e >> 3) + 2 * col) & 31) << 4) + ((e & 7) << 1);
  *(u16*)(wout + b0) = f16bits(v);
}

// ============================================================
// Kernel 2: QKV projection. Grid (1024, 6) x 256 thr.
// Block = 64 tokens x 128 cols of one matrix; 64KB half-weight staged once.
// Wave = 16 tokens; x read fp32 directly, split fp16 hi/lo in regs.
// Q,K: 2-term fp16. V: 2-term, swapped operands (C rows = d).
// Outputs: qh/ql [tok][256] fp16; kh [tok][512B swizzled] fp16;
// vt tiled [b][tile32][256d][32t] fp16 XOR-swizzled.
// ============================================================
__global__ __launch_bounds__(256, 2) void proj_kernel(
    const float* __restrict__ x, const float* __restrict__ bq,
    const float* __restrict__ bk, const float* __restrict__ bv,
    const char* __restrict__ wspl,
    u16* __restrict__ qh, u16* __restrict__ ql,
    char* __restrict__ kh, char* __restrict__ vt) {
  __shared__ __align__(16) char wlds[65536];
  const int tid = threadIdx.x;
  const int l = tid & 63, w = tid >> 6;     // 4 waves
  const int l15 = l & 15, l4 = l >> 4;
  const int g = blockIdx.y;
  const int mat = g >> 1, half = g & 1;
  const int tok0 = blockIdx.x * 64 + w * 16;

  // ---- stage 64KB half-weight ----
  {
    const char* wsrc = wspl + (size_t)g * 65536;
    #pragma unroll
    for (int i = 0; i < 16; i++)
      gl_lds16(wsrc + i * 4096 + w * 1024 + l * 16, wlds + i * 4096 + w * 1024);
  }

  // ---- x fp32 -> hi/lo fp16 A-frags (16 tok/wave) ----
  f16x8 xh8[8], xl8[8];
  {
    const float* xp = x + (size_t)(tok0 + l15) * 256;
    #pragma unroll
    for (int kk = 0; kk < 8; kk++) {
      const float* p = xp + kk * 32 + l4 * 8;
      float4 f0 = *(const float4*)p;
      float4 f1 = *(const float4*)(p + 4);
      float ff[8] = {f0.x, f0.y, f0.z, f0.w, f1.x, f1.y, f1.z, f1.w};
      union { u16 s[8]; f16x8 v; } H, L;
      #pragma unroll
      for (int e = 0; e < 8; e++) {
        f16 h = (f16)ff[e];
        union { f16 h; u16 u; } uh; uh.h = h; H.s[e] = uh.u;
        union { f16 h; u16 u; } ul; ul.h = (f16)(ff[e] - (float)h); L.s[e] = ul.u;
      }
      xh8[kk] = H.v;
      xl8[kk] = L.v;
    }
  }
  __syncthreads();   // weights staged (syncthreads drains vmcnt)

  f32x4 acc[8];
  #pragma unroll
  for (int i = 0; i < 8; i++) acc[i] = (f32x4){0.f, 0.f, 0.f, 0.f};

  #pragma unroll
  for (int kk = 0; kk < 8; kk++) {
    f16x8 ah = xh8[kk];
    f16x8 al = xl8[kk];
    #pragma unroll
    for (int ct = 0; ct < 8; ct++) {
      int off = (ct * 16 + l15) * 512 + (((kk * 4 + l4 + 2 * l15) & 31) << 4);
      f16x8 bh = *(const f16x8*)(wlds + off);
      if (mat < 2) {
        acc[ct] = mfma16h(ah, bh, acc[ct]);
        acc[ct] = mfma16h(al, bh, acc[ct]);
      } else {
        acc[ct] = mfma16h(bh, ah, acc[ct]);   // swapped: C rows = d, cols = tok
        acc[ct] = mfma16h(bh, al, acc[ct]);
      }
    }
  }

  // ---- epilogues ----
  if (mat == 0) {
    #pragma unroll
    for (int ct = 0; ct < 8; ct++) {
      int col = half * 128 + ct * 16 + l15;
      float bb = bq[col];
      #pragma unroll
      for (int j = 0; j < 4; j++) {
        size_t tok = (size_t)(tok0 + l4 * 4 + j);
        float v = acc[ct][j] + bb;
        f16 hi = (f16)v;
        union { f16 h; u16 u; } uh; uh.h = hi;
        union { f16 h; u16 u; } ul; ul.h = (f16)(v - (float)hi);
        qh[tok * 256 + col] = uh.u;
        ql[tok * 256 + col] = ul.u;
      }
    }
  } else if (mat == 1) {
    #pragma unroll
    for (int ct = 0; ct < 8; ct++) {
      int col = half * 128 + ct * 16 + l15;
      float bb = bk[col];
      #pragma unroll
      for (int j = 0; j < 4; j++) {
        size_t tok = (size_t)(tok0 + l4 * 4 + j);
        float v = acc[ct][j] + bb;
        size_t off = tok * 512 + ((((col >> 3) + 2 * (int)tok) & 31) << 4)
                   + ((col & 7) << 1);
        *(u16*)(kh + off) = f16bits(v);
      }
    }
  } else {
    int t = tok0 + l15;
    int b2 = t >> 10, tile = (t >> 5) & 31, trel = t & 31;
    size_t tbase = (size_t)b2 * 524288 + (size_t)tile * 16384
                 + ((trel & 7) << 1);
    int tsl = (trel >> 3) << 4;
    #pragma unroll
    for (int ct = 0; ct < 8; ct++) {
      #pragma unroll
      for (int j = 0; j < 4; j++) {
        int d = half * 128 + ct * 16 + l4 * 4 + j;
        float v = acc[ct][j] + bv[d];
        size_t off = tbase + ((d * 64 + tsl) ^ ((d & 7) << 4));
        *(u16*)(vt + off) = f16bits(v);
      }
    }
  }
}

// ============================================================
// Kernel 3: flash attention. Grid 1024 x 256 thr; block = 64 q rows
// (4 waves x 16), KVBLK=64. Single 64KB K/V buffer, gl_lds stage ->
// syncthreads -> compute (r2-proven pattern); 72KB LDS -> 2 blocks/CU.
// 2-term fp16 scores; defer-max THR=8; fp16 PV; setprio on MFMA.
// XCD swizzle: all 16 q-blocks of a batch on one XCD.
// ============================================================
__global__ __launch_bounds__(256, 2) void attn_kernel(
    const u16* __restrict__ qh_g, const u16* __restrict__ ql_g,
    const char* __restrict__ kh_g, const char* __restrict__ vt_g,
    float* __restrict__ out) {
  __shared__ __align__(16) char lds[73728];
  char* kh_lds = lds;            // [64][512B swz] = 32KB
  char* vt_lds = lds + 32768;    // 2 subtiles [256d][64B swz] = 32KB
  char* p_lds  = lds + 65536;    // 4 waves x 2KB

  const int tid = threadIdx.x;
  const int l = tid & 63, w = tid >> 6;   // 4 waves
  const int l15 = l & 15, l4 = l >> 4;
  int wg = blockIdx.x;
  int b  = (wg & 7) * 8 + (wg >> 7);      // XCD-grouped batches
  int qt = (wg >> 3) & 15;

  // ---- Q fragments (16 rows/wave, hi/lo fp16) ----
  const int q0 = qt * 64 + w * 16;
  const char* qhp = (const char*)qh_g + (size_t)(b * 1024 + q0 + l15) * 512 + l4 * 16;
  const char* qlp = (const char*)ql_g + (size_t)(b * 1024 + q0 + l15) * 512 + l4 * 16;
  f16x8 qfh[8], qfl[8];
  #pragma unroll
  for (int kk = 0; kk < 8; kk++) {
    qfh[kk] = *(const f16x8*)(qhp + kk * 64);
    qfl[kk] = *(const f16x8*)(qlp + kk * 64);
  }

  f32x4 O[16];
  #pragma unroll
  for (int i = 0; i < 16; i++) O[i] = (f32x4){0.f, 0.f, 0.f, 0.f};
  float mrow[4] = {-1e30f, -1e30f, -1e30f, -1e30f};
  float lrow[4] = {0.f, 0.f, 0.f, 0.f};

  const char* khb = kh_g + (size_t)b * 524288;
  const char* vtb = vt_g + (size_t)b * 524288;
  char* pw = p_lds + w * 2048;

  for (int t0 = 0; t0 < 1024; t0 += 64) {
    __syncthreads();   // all waves done with previous tile's LDS
    // ---- stage K (32KB) + V 2 subtiles (32KB) via gl_lds ----
    {
      const char* ks = khb + (size_t)t0 * 512;
      const char* vs = vtb + (size_t)(t0 >> 5) * 16384;
      #pragma unroll
      for (int i = 0; i < 8; i++) {
        int co = i * 4096 + w * 1024;
        gl_lds16(ks + co + l * 16, kh_lds + co);
        gl_lds16(vs + co + l * 16, vt_lds + co);
      }
    }
    __syncthreads();   // staged (syncthreads drains vmcnt)

    // ---- scores: S[16q][64t], 2-term fp16 ----
    f32x4 sacc[4];
    #pragma unroll
    for (int c = 0; c < 4; c++) sacc[c] = (f32x4){0.f, 0.f, 0.f, 0.f};
    __builtin_amdgcn_s_setprio(1);
    #pragma unroll
    for (int kk = 0; kk < 8; kk++) {
      int so = ((kk * 4 + l4 + 2 * l15) & 31) << 4;
      #pragma unroll
      for (int c = 0; c < 4; c++) {
        f16x8 bh = *(const f16x8*)(kh_lds + (c * 16 + l15) * 512 + so);
        sacc[c] = mfma16h(qfh[kk], bh, sacc[c]);
        sacc[c] = mfma16h(qfl[kk], bh, sacc[c]);
      }
    }
    __builtin_amdgcn_s_setprio(0);

    // ---- online softmax with defer-max (THR=8) ----
    float p[4][4];
    {
      bool need = false;
      float lmax[4];
      #pragma unroll
      for (int j = 0; j < 4; j++) {
        lmax[j] = fmaxf(fmaxf(sacc[0][j], sacc[1][j]),
                        fmaxf(sacc[2][j], sacc[3][j]));
        need = need || (lmax[j] > mrow[j] + 8.f);
      }
      if (__any(need)) {
        float scv[4];
        #pragma unroll
        for (int j = 0; j < 4; j++) {
          float mx = lmax[j];
          mx = fmaxf(mx, __shfl_xor(mx, 1));
          mx = fmaxf(mx, __shfl_xor(mx, 2));
          mx = fmaxf(mx, __shfl_xor(mx, 4));
          mx = fmaxf(mx, __shfl_xor(mx, 8));
          float mn = fmaxf(mrow[j], mx);
          scv[j] = __expf(mrow[j] - mn);
          mrow[j] = mn;
          lrow[j] *= scv[j];
        }
        #pragma unroll
        for (int i = 0; i < 16; i++) {
          O[i][0] *= scv[0]; O[i][1] *= scv[1];
          O[i][2] *= scv[2]; O[i][3] *= scv[3];
        }
      }
      #pragma unroll
      for (int j = 0; j < 4; j++) {
        float rs = 0.f;
        #pragma unroll
        for (int c = 0; c < 4; c++) {
          p[c][j] = __expf(sacc[c][j] - mrow[j]);
          rs += p[c][j];
        }
        rs += __shfl_xor(rs, 1);
        rs += __shfl_xor(rs, 2);
        rs += __shfl_xor(rs, 4);
        rs += __shfl_xor(rs, 8);
        lrow[j] += rs;
      }
    }

    // ---- P -> per-wave LDS (fp16), re-fragment for PV ----
    #pragma unroll
    for (int j = 0; j < 4; j++) {
      int row = l4 * 4 + j;
      int base = row << 7;
      int sw = (row & 7) << 4;
      #pragma unroll
      for (int c = 0; c < 4; c++)
        *(u16*)(pw + base + ((((c * 16 + l15) << 1)) ^ sw)) = f16bits(p[c][j]);
    }
    asm volatile("s_waitcnt lgkmcnt(0)" ::: "memory");
    __builtin_amdgcn_sched_barrier(0);
    int psw = (l15 & 7) << 4;
    f16x8 pa0 = *(const f16x8*)(pw + (l15 << 7) + ((l4 * 16) ^ psw));
    f16x8 pa1 = *(const f16x8*)(pw + (l15 << 7) + ((64 + l4 * 16) ^ psw));

    // ---- PV: O += P * V ----
    __builtin_amdgcn_s_setprio(1);
    #pragma unroll
    for (int dt = 0; dt < 16; dt++) {
      int d = dt * 16 + l15;
      int vo = (d * 64 + l4 * 16) ^ ((d & 7) << 4);
      f16x8 vb0 = *(const f16x8*)(vt_lds + vo);
      f16x8 vb1 = *(const f16x8*)(vt_lds + 16384 + vo);
      O[dt] = mfma16h(pa0, vb0, O[dt]);
      O[dt] = mfma16h(pa1, vb1, O[dt]);
    }
    __builtin_amdgcn_s_setprio(0);
  }

  // ---- epilogue ----
  float inv[4];
  #pragma unroll
  for (int j = 0; j < 4; j++) inv[j] = 1.0f / lrow[j];
  #pragma unroll
  for (int dt = 0; dt < 16; dt++) {
    #pragma unroll
    for (int j = 0; j < 4; j++) {
      size_t orow = (size_t)(b * 1024 + q0 + l4 * 4 + j);
      out[orow * 256 + dt * 16 + l15] = O[dt][j] * inv[j];
    }
  }
}

// ============================================================
extern "C" void kernel_launch(void* const* d_in, const int* in_sizes, int n_in,
                              void* d_out, int out_size, void* d_ws, size_t ws_size,
                              hipStream_t stream) {
  (void)in_sizes; (void)n_in; (void)out_size; (void)ws_size;
  const float* x  = (const float*)d_in[0];
  const float* Wq = (const float*)d_in[1];
  const float* bq = (const float*)d_in[2];
  const float* Wk = (const float*)d_in[3];
  const float* bk = (const float*)d_in[4];
  const float* Wv = (const float*)d_in[5];
  const float* bv = (const float*)d_in[6];
  float* out = (float*)d_out;
  char* ws = (char*)d_ws;

  const size_t M32 = 33554432;
  u16* qh  = (u16*)(ws);
  u16* ql  = (u16*)(ws + M32);
  char* kh = (char*)(ws + 2 * M32);
  char* vt = (char*)(ws + 3 * M32);
  char* wsp = (char*)(ws + 4 * M32);   // 384KB fp16 weights

  prep_w_kernel<<<dim3(768), dim3(256), 0, stream>>>(Wq, Wk, Wv, wsp);
  proj_kernel<<<dim3(1024, 6), dim3(256), 0, stream>>>(
      x, bq, bk, bv, wsp, qh, ql, kh, vt);
  attn_kernel<<<dim3(1024), dim3(256), 0, stream>>>(qh, ql, kh, vt, out);
}